// Round 3
// baseline (60.300 us; speedup 1.0000x reference)
//
#include <hip/hip_runtime.h>

#define MARGIN 1.0f
#define NBLOCKS 2048   // 8 blocks/CU x 256 CUs: one fully-resident generation
#define NT 256

// Grid-stride over rows; per-block partial -> d_ws[blockIdx.x]. No atomics.
// The c==target term contributes exactly MARGIN per row; corrected in finalize.
// ILP: 4 float4 loads in flight per thread (4 accumulators), and the next
// row's correct-class gather is prefetched under the current row's stream.
__global__ __launch_bounds__(NT) void mcl_hinge(const float* __restrict__ score,
                                                const int* __restrict__ target,
                                                double* __restrict__ partial,
                                                int N, int C) {
    const int gs = gridDim.x;
    const int nvec = C >> 2;

    float acc0 = 0.0f, acc1 = 0.0f, acc2 = 0.0f, acc3 = 0.0f;

    int row = blockIdx.x;
    float c_cur = (row < N) ? score[(size_t)row * C + target[row]] : 0.0f;

    for (; row < N; row += gs) {
        const float b = MARGIN - c_cur;

        // prefetch next row's correct-class score; its ~2-load dependent
        // chain hides under this row's ~1250-load stream
        const int nrow = row + gs;
        if (nrow < N) c_cur = score[(size_t)nrow * C + target[nrow]];

        const size_t base = (size_t)row * (size_t)C;
        const float4* __restrict__ rp = reinterpret_cast<const float4*>(score + base);

        int i = threadIdx.x;
        // 4 independent loads in flight per iteration
        for (; i + 3 * NT < nvec; i += 4 * NT) {
            float4 v0 = rp[i];
            float4 v1 = rp[i +     NT];
            float4 v2 = rp[i + 2 * NT];
            float4 v3 = rp[i + 3 * NT];
            acc0 += fmaxf(0.0f, v0.x + b); acc0 += fmaxf(0.0f, v0.y + b);
            acc0 += fmaxf(0.0f, v0.z + b); acc0 += fmaxf(0.0f, v0.w + b);
            acc1 += fmaxf(0.0f, v1.x + b); acc1 += fmaxf(0.0f, v1.y + b);
            acc1 += fmaxf(0.0f, v1.z + b); acc1 += fmaxf(0.0f, v1.w + b);
            acc2 += fmaxf(0.0f, v2.x + b); acc2 += fmaxf(0.0f, v2.y + b);
            acc2 += fmaxf(0.0f, v2.z + b); acc2 += fmaxf(0.0f, v2.w + b);
            acc3 += fmaxf(0.0f, v3.x + b); acc3 += fmaxf(0.0f, v3.y + b);
            acc3 += fmaxf(0.0f, v3.z + b); acc3 += fmaxf(0.0f, v3.w + b);
        }
        // remainder float4 slots (one predicated slot for C=5000)
        for (; i < nvec; i += NT) {
            float4 v = rp[i];
            acc0 += fmaxf(0.0f, v.x + b); acc0 += fmaxf(0.0f, v.y + b);
            acc0 += fmaxf(0.0f, v.z + b); acc0 += fmaxf(0.0f, v.w + b);
        }
        // scalar tail for C % 4 (empty for C=5000)
        for (int j = (nvec << 2) + (int)threadIdx.x; j < C; j += NT)
            acc1 += fmaxf(0.0f, score[base + j] + b);
    }

    float acc = (acc0 + acc1) + (acc2 + acc3);

    // 64-lane wave reduce, then cross-wave via LDS
    #pragma unroll
    for (int off = 32; off > 0; off >>= 1)
        acc += __shfl_down(acc, off, 64);

    __shared__ float warp_s[NT / 64];
    const int lane = threadIdx.x & 63;
    const int wid  = threadIdx.x >> 6;
    if (lane == 0) warp_s[wid] = acc;
    __syncthreads();
    if (threadIdx.x == 0)
        partial[blockIdx.x] = (double)(warp_s[0] + warp_s[1] + warp_s[2] + warp_s[3]);
}

// One block reduces the NBLOCKS doubles and finalizes the mean.
__global__ __launch_bounds__(256) void mcl_final(const double* __restrict__ partial,
                                                 float* __restrict__ out,
                                                 int NB, int N, int C) {
    double s = 0.0;
    for (int i = threadIdx.x; i < NB; i += 256) s += partial[i];

    #pragma unroll
    for (int off = 32; off > 0; off >>= 1)
        s += __shfl_down(s, off, 64);

    __shared__ double warp_s[4];
    const int lane = threadIdx.x & 63;
    const int wid  = threadIdx.x >> 6;
    if (lane == 0) warp_s[wid] = s;
    __syncthreads();
    if (threadIdx.x == 0) {
        double tot = warp_s[0] + warp_s[1] + warp_s[2] + warp_s[3];
        tot -= (double)N * (double)MARGIN;              // remove c==target terms
        out[0] = (float)(tot / ((double)N * (double)(C - 1)));
    }
}

extern "C" void kernel_launch(void* const* d_in, const int* in_sizes, int n_in,
                              void* d_out, int out_size, void* d_ws, size_t ws_size,
                              hipStream_t stream) {
    const float* score  = (const float*)d_in[0];
    const int*   target = (const int*)d_in[1];
    float* out = (float*)d_out;
    double* ws = (double*)d_ws;   // NBLOCKS doubles = 16 KB of scratch

    const int N = in_sizes[1];
    const int C = in_sizes[0] / N;

    mcl_hinge<<<NBLOCKS, NT, 0, stream>>>(score, target, ws, N, C);
    mcl_final<<<1, 256, 0, stream>>>(ws, out, NBLOCKS, N, C);
}

// Round 4
// 58.492 us; speedup vs baseline: 1.0309x; 1.0309x over previous
//
#include <hip/hip_runtime.h>

#define MARGIN 1.0f
#define NT 256
#define ROWS_PER_BLOCK 8

// ---- specialized flat kernel (compile-time C) --------------------------------
// Block b owns contiguous rows [8b, 8b+8) = TOT float4s. Threads 0-7 gather the
// 8 correct-class scores into LDS once; then a fully-uniform flat stream with
// row lookup via constant-divisor magic-mul + LDS broadcast.
template <int CC>
__global__ __launch_bounds__(NT) void mcl_hinge_flat(const float* __restrict__ score,
                                                     const int* __restrict__ target,
                                                     double* __restrict__ partial) {
    constexpr int NV  = CC / 4;               // float4 per row (1250)
    constexpr int TOT = ROWS_PER_BLOCK * NV;  // float4 per block (10000)
    constexpr int KFULL = (TOT - (NT - 1) + NT - 1) / NT;  // uniform iters = 39
    constexpr int TAIL  = TOT - KFULL * NT;                // leftover slots = 16

    __shared__ float lb[ROWS_PER_BLOCK];
    const int r0 = blockIdx.x * ROWS_PER_BLOCK;
    if (threadIdx.x < ROWS_PER_BLOCK) {
        const int r = r0 + threadIdx.x;
        lb[threadIdx.x] = MARGIN - score[(size_t)r * CC + target[r]];
    }
    __syncthreads();

    const float4* __restrict__ rp =
        reinterpret_cast<const float4*>(score) + (size_t)blockIdx.x * TOT;

    float acc0 = 0.0f, acc1 = 0.0f;
    int f = threadIdx.x;
    #pragma unroll 3
    for (int k = 0; k < KFULL; ++k, f += NT) {   // no predication: 39*256 <= TOT
        const float b = lb[f / NV];              // constant divisor -> magic mul
        const float4 v = rp[f];
        acc0 += fmaxf(0.0f, v.x + b) + fmaxf(0.0f, v.y + b);
        acc1 += fmaxf(0.0f, v.z + b) + fmaxf(0.0f, v.w + b);
    }
    if (TAIL > 0 && threadIdx.x < TAIL) {        // 16 threads, one extra slot
        const float b = lb[f / NV];
        const float4 v = rp[f];
        acc0 += fmaxf(0.0f, v.x + b) + fmaxf(0.0f, v.y + b);
        acc1 += fmaxf(0.0f, v.z + b) + fmaxf(0.0f, v.w + b);
    }
    float acc = acc0 + acc1;

    #pragma unroll
    for (int off = 32; off > 0; off >>= 1)
        acc += __shfl_down(acc, off, 64);

    __shared__ float warp_s[NT / 64];
    if ((threadIdx.x & 63) == 0) warp_s[threadIdx.x >> 6] = acc;
    __syncthreads();
    if (threadIdx.x == 0)
        partial[blockIdx.x] = (double)(warp_s[0] + warp_s[1] + warp_s[2] + warp_s[3]);
}

// ---- generic fallback (round-2 structure) -----------------------------------
__global__ __launch_bounds__(NT) void mcl_hinge_gen(const float* __restrict__ score,
                                                    const int* __restrict__ target,
                                                    double* __restrict__ partial,
                                                    int N, int C) {
    float acc = 0.0f;
    const int nvec = C >> 2;
    for (int row = blockIdx.x; row < N; row += gridDim.x) {
        const size_t base = (size_t)row * (size_t)C;
        const float b = MARGIN - score[base + target[row]];
        const float4* __restrict__ rp = reinterpret_cast<const float4*>(score + base);
        for (int i = threadIdx.x; i < nvec; i += NT) {
            float4 v = rp[i];
            acc += fmaxf(0.0f, v.x + b) + fmaxf(0.0f, v.y + b)
                 + fmaxf(0.0f, v.z + b) + fmaxf(0.0f, v.w + b);
        }
        for (int i = (nvec << 2) + (int)threadIdx.x; i < C; i += NT)
            acc += fmaxf(0.0f, score[base + i] + b);
    }
    #pragma unroll
    for (int off = 32; off > 0; off >>= 1)
        acc += __shfl_down(acc, off, 64);
    __shared__ float warp_s[NT / 64];
    if ((threadIdx.x & 63) == 0) warp_s[threadIdx.x >> 6] = acc;
    __syncthreads();
    if (threadIdx.x == 0)
        partial[blockIdx.x] = (double)(warp_s[0] + warp_s[1] + warp_s[2] + warp_s[3]);
}

// ---- final reduce ------------------------------------------------------------
__global__ __launch_bounds__(256) void mcl_final(const double* __restrict__ partial,
                                                 float* __restrict__ out,
                                                 int NB, int N, int C) {
    double s = 0.0;
    for (int i = threadIdx.x; i < NB; i += 256) s += partial[i];
    #pragma unroll
    for (int off = 32; off > 0; off >>= 1)
        s += __shfl_down(s, off, 64);
    __shared__ double warp_s[4];
    if ((threadIdx.x & 63) == 0) warp_s[threadIdx.x >> 6] = s;
    __syncthreads();
    if (threadIdx.x == 0) {
        double tot = warp_s[0] + warp_s[1] + warp_s[2] + warp_s[3];
        tot -= (double)N * (double)MARGIN;   // remove the c==target terms
        out[0] = (float)(tot / ((double)N * (double)(C - 1)));
    }
}

extern "C" void kernel_launch(void* const* d_in, const int* in_sizes, int n_in,
                              void* d_out, int out_size, void* d_ws, size_t ws_size,
                              hipStream_t stream) {
    const float* score  = (const float*)d_in[0];
    const int*   target = (const int*)d_in[1];
    float* out = (float*)d_out;
    double* ws = (double*)d_ws;

    const int N = in_sizes[1];
    const int C = in_sizes[0] / N;

    if (C == 5000 && (N % ROWS_PER_BLOCK) == 0) {
        const int nb = N / ROWS_PER_BLOCK;   // 2048
        mcl_hinge_flat<5000><<<nb, NT, 0, stream>>>(score, target, ws);
        mcl_final<<<1, 256, 0, stream>>>(ws, out, nb, N, C);
    } else {
        const int nb = 2048;
        mcl_hinge_gen<<<nb, NT, 0, stream>>>(score, target, ws, N, C);
        mcl_final<<<1, 256, 0, stream>>>(ws, out, nb, N, C);
    }
}